// Round 1
// baseline (24807.370 us; speedup 1.0000x reference)
//
#include <hip/hip_runtime.h>
#include <hip/hip_bf16.h>
#include <math.h>

// Model dims
constexpr int kD = 1024;
constexpr int kH = 16;
constexpr int kHD = 64;
constexpr int kV = 32000;
constexpr int kT = 1024;
constexpr int kG = 16;
constexpr int kg = 64;
constexpr int kFF = 4096;
constexpr int kL = 24;
constexpr int kNTRI = 2016;
#define EPSF 1e-6f

// ---------------------------------------------------------------------------
// Cayley transform: R = (I - A/2)^-1 (I + A/2), one block per (layer,group),
// 64 threads = 64 rows, Gauss-Jordan in LDS. M is diag-dominant (|A|~0.02),
// no pivoting needed.
// ---------------------------------------------------------------------------
__global__ __launch_bounds__(64) void cayley_kernel(const float* __restrict__ skew,
                                                    float* __restrict__ R) {
  int lg = blockIdx.x;
  int r = threadIdx.x;
  __shared__ float Ms[64][65];
  __shared__ float Bs[64][65];
  const float* su = skew + (size_t)lg * kNTRI;
  for (int c = 0; c < 64; ++c) {
    float a = 0.f;
    if (r < c) a = su[r * (127 - r) / 2 + (c - r - 1)];
    else if (r > c) a = -su[c * (127 - c) / 2 + (r - c - 1)];
    Ms[r][c] = (r == c ? 1.f : 0.f) - 0.5f * a;
    Bs[r][c] = (r == c ? 1.f : 0.f) + 0.5f * a;
  }
  __syncthreads();
  for (int k = 0; k < 64; ++k) {
    if (r == k) {
      float piv = 1.f / Ms[k][k];
      for (int c = 0; c < 64; ++c) { Ms[k][c] *= piv; Bs[k][c] *= piv; }
    }
    __syncthreads();
    if (r != k) {
      float f = Ms[r][k];
      for (int c = 0; c < 64; ++c) { Ms[r][c] -= f * Ms[k][c]; Bs[r][c] -= f * Bs[k][c]; }
    }
    __syncthreads();
  }
  float* Ro = R + ((size_t)lg * 64 + r) * 64;
  for (int c = 0; c < 64; ++c) Ro[c] = Bs[r][c];
}

// ---------------------------------------------------------------------------
// Embedding gather, float4-vectorized.
// ---------------------------------------------------------------------------
__global__ __launch_bounds__(256) void embed_kernel(const int* __restrict__ tok,
                                                    const float* __restrict__ ew,
                                                    float* __restrict__ x) {
  int i = blockIdx.x * 256 + threadIdx.x;  // over T*D/4
  int t = i >> 8;                          // D/4 = 256 float4 per row
  int d4 = i & 255;
  int v = tok[t];
  reinterpret_cast<float4*>(x)[i] =
      reinterpret_cast<const float4*>(ew + (size_t)v * kD)[d4];
}

// ---------------------------------------------------------------------------
// RMSNorm (one block per row, 256 threads * float4 = 1024 elems).
// AFFINE: out = rms(x)*w*gamma + beta   else: out = rms(x)*w
// ---------------------------------------------------------------------------
template <bool AFFINE>
__global__ __launch_bounds__(256) void rms_kernel(const float* __restrict__ x,
                                                  const float* __restrict__ w,
                                                  const float* __restrict__ gamma,
                                                  const float* __restrict__ beta,
                                                  float* __restrict__ out) {
  int t = blockIdx.x, tid = threadIdx.x;
  __shared__ float red[256];
  float4 xv = reinterpret_cast<const float4*>(x + (size_t)t * kD)[tid];
  red[tid] = xv.x * xv.x + xv.y * xv.y + xv.z * xv.z + xv.w * xv.w;
  __syncthreads();
  for (int off = 128; off > 0; off >>= 1) {
    if (tid < off) red[tid] += red[tid + off];
    __syncthreads();
  }
  float rms = rsqrtf(red[0] / (float)kD + EPSF);
  float4 wv = reinterpret_cast<const float4*>(w)[tid];
  float4 o;
  o.x = xv.x * rms * wv.x;
  o.y = xv.y * rms * wv.y;
  o.z = xv.z * rms * wv.z;
  o.w = xv.w * rms * wv.w;
  if (AFFINE) {
    float4 gv = reinterpret_cast<const float4*>(gamma)[tid];
    float4 bv = reinterpret_cast<const float4*>(beta)[tid];
    o.x = o.x * gv.x + bv.x;
    o.y = o.y * gv.y + bv.y;
    o.z = o.z * gv.z + bv.z;
    o.w = o.w * gv.w + bv.w;
  }
  reinterpret_cast<float4*>(out + (size_t)t * kD)[tid] = o;
}

// ---------------------------------------------------------------------------
// f32 GEMM: C[M,N] = A[M,K] @ B  (+ epilogue)
// BT=false: B is [K,N] row-major.  BT=true: B is [N,K] row-major (B^T).
// EPI: 0 = store, 1 = store acc+res, 2 = gelu(tanh) then store.
// 64x64 tile, BK=16, 256 threads, 4x4 per thread. All dims divide tiles.
// ---------------------------------------------------------------------------
template <int EPI, bool BT>
__global__ __launch_bounds__(256) void gemm_kernel(const float* __restrict__ A,
                                                   const float* __restrict__ B,
                                                   const float* res,
                                                   float* C,
                                                   int M, int N, int K) {
  __shared__ float As[16][64];  // As[k][m]
  __shared__ float Bs[16][64];  // Bs[k][n]
  int tid = threadIdx.x;
  int tx = tid & 15, ty = tid >> 4;
  int bn = blockIdx.x * 64, bm = blockIdx.y * 64;
  int arow = tid >> 2, akq = (tid & 3) << 2;
  int bkr = tid >> 4, bn4 = (tid & 15) << 2;
  float acc[4][4] = {};
  for (int k0 = 0; k0 < K; k0 += 16) {
    float4 av = *reinterpret_cast<const float4*>(A + (size_t)(bm + arow) * K + k0 + akq);
    As[akq + 0][arow] = av.x;
    As[akq + 1][arow] = av.y;
    As[akq + 2][arow] = av.z;
    As[akq + 3][arow] = av.w;
    if (!BT) {
      float4 bv = *reinterpret_cast<const float4*>(B + (size_t)(k0 + bkr) * N + bn + bn4);
      *reinterpret_cast<float4*>(&Bs[bkr][bn4]) = bv;
    } else {
      float4 bv = *reinterpret_cast<const float4*>(B + (size_t)(bn + arow) * K + k0 + akq);
      Bs[akq + 0][arow] = bv.x;
      Bs[akq + 1][arow] = bv.y;
      Bs[akq + 2][arow] = bv.z;
      Bs[akq + 3][arow] = bv.w;
    }
    __syncthreads();
#pragma unroll
    for (int k = 0; k < 16; ++k) {
      float4 a4 = *reinterpret_cast<const float4*>(&As[k][ty << 2]);
      float4 b4 = *reinterpret_cast<const float4*>(&Bs[k][tx << 2]);
      float af[4] = {a4.x, a4.y, a4.z, a4.w};
      float bf[4] = {b4.x, b4.y, b4.z, b4.w};
#pragma unroll
      for (int i = 0; i < 4; ++i)
#pragma unroll
        for (int j = 0; j < 4; ++j) acc[i][j] += af[i] * bf[j];
    }
    __syncthreads();
  }
#pragma unroll
  for (int i = 0; i < 4; ++i) {
    int row = bm + (ty << 2) + i;
#pragma unroll
    for (int j = 0; j < 4; ++j) {
      int col = bn + (tx << 2) + j;
      size_t idx = (size_t)row * N + col;
      float v = acc[i][j];
      if (EPI == 1) v += res[idx];
      if (EPI == 2) {
        float u = v;
        v = 0.5f * u * (1.f + tanhf(0.7978845608028654f * (u + 0.044715f * u * u * u)));
      }
      C[idx] = v;
    }
  }
}

// ---------------------------------------------------------------------------
// Causal attention, one block per (q, head). qkv layout: [T][3D] with
// q at [t][h*64+d], k at [t][D+h*64+d], v at [t][2D+h*64+d].
// Scores for k<=q staged in LDS, softmax, then PV with 4 waves.
// ---------------------------------------------------------------------------
__global__ __launch_bounds__(256) void attn_kernel(const float* __restrict__ qkv,
                                                   float* __restrict__ out) {
  int q = blockIdx.x, h = blockIdx.y;
  int tid = threadIdx.x;
  __shared__ float qv[64];
  __shared__ float sc[kT];
  __shared__ float red[256];
  __shared__ float part[4][64];
  const float* qrow = qkv + (size_t)q * (3 * kD) + h * 64;
  if (tid < 64) qv[tid] = qrow[tid];
  __syncthreads();
  int nk = q + 1;
  float lmax = -1e30f;
  for (int k = tid; k < nk; k += 256) {
    const float* krow = qkv + (size_t)k * (3 * kD) + kD + h * 64;
    float s = 0.f;
#pragma unroll
    for (int d = 0; d < 64; d += 4) {
      float4 k4 = *reinterpret_cast<const float4*>(krow + d);
      float4 q4 = *reinterpret_cast<const float4*>(&qv[d]);
      s += q4.x * k4.x + q4.y * k4.y + q4.z * k4.z + q4.w * k4.w;
    }
    s *= 0.125f;  // 1/sqrt(64)
    sc[k] = s;
    lmax = fmaxf(lmax, s);
  }
  red[tid] = lmax;
  __syncthreads();
  for (int off = 128; off > 0; off >>= 1) {
    if (tid < off) red[tid] = fmaxf(red[tid], red[tid + off]);
    __syncthreads();
  }
  float m = red[0];
  __syncthreads();
  float lsum = 0.f;
  for (int k = tid; k < nk; k += 256) {
    float e = expf(sc[k] - m);
    sc[k] = e;
    lsum += e;
  }
  red[tid] = lsum;
  __syncthreads();
  for (int off = 128; off > 0; off >>= 1) {
    if (tid < off) red[tid] += red[tid + off];
    __syncthreads();
  }
  float inv = 1.f / red[0];
  int w = tid >> 6, lane = tid & 63;
  float accv = 0.f;
  for (int k = w; k < nk; k += 4)
    accv += sc[k] * qkv[(size_t)k * (3 * kD) + 2 * kD + h * 64 + lane];
  part[w][lane] = accv;
  __syncthreads();
  if (tid < 64) {
    float o = (part[0][tid] + part[1][tid] + part[2][tid] + part[3][tid]) * inv;
    out[(size_t)q * kD + h * 64 + tid] = o;
  }
}

// ---------------------------------------------------------------------------
// Fused residual blend + group rotation:
// xb = x + (y - x) * its[l];  xout[t][g*64+j] = sum_i xb[t][g*64+i] * R[l][g][i][j]
// One block per token row.
// ---------------------------------------------------------------------------
__global__ __launch_bounds__(256) void blend_rot_kernel(const float* __restrict__ x,
                                                        const float* __restrict__ y,
                                                        const float* __restrict__ iscale,
                                                        int l,
                                                        const float* __restrict__ R,
                                                        float* __restrict__ xout) {
  int t = blockIdx.x, tid = threadIdx.x;
  __shared__ float xb[kD];
  float s = iscale[l];
  float4 xv = reinterpret_cast<const float4*>(x + (size_t)t * kD)[tid];
  float4 yv = reinterpret_cast<const float4*>(y + (size_t)t * kD)[tid];
  xb[4 * tid + 0] = xv.x + (yv.x - xv.x) * s;
  xb[4 * tid + 1] = xv.y + (yv.y - xv.y) * s;
  xb[4 * tid + 2] = xv.z + (yv.z - xv.z) * s;
  xb[4 * tid + 3] = xv.w + (yv.w - xv.w) * s;
  __syncthreads();
  const float* Rl = R + (size_t)l * kG * 64 * 64;
#pragma unroll
  for (int rep = 0; rep < 4; ++rep) {
    int oi = rep * 256 + tid;
    int gr = oi >> 6, j = oi & 63;
    const float* Rg = Rl + ((size_t)gr << 12);
    const float* xg = &xb[gr << 6];
    float acc = 0.f;
#pragma unroll 8
    for (int i = 0; i < 64; ++i) acc += xg[i] * Rg[(i << 6) + j];
    xout[(size_t)t * kD + oi] = acc;
  }
}

// ---------------------------------------------------------------------------
extern "C" void kernel_launch(void* const* d_in, const int* in_sizes, int n_in,
                              void* d_out, int out_size, void* d_ws, size_t ws_size,
                              hipStream_t stream) {
  const int* tokens = (const int*)d_in[0];
  const float* embed_w = (const float*)d_in[1];
  const float* lm_head_w = (const float*)d_in[2];
  const float* norm_w = (const float*)d_in[3];
  const float* layer_gamma = (const float*)d_in[4];
  const float* layer_beta = (const float*)d_in[5];
  const float* iter_scale = (const float*)d_in[6];
  const float* skew_upper = (const float*)d_in[7];
  const float* ln1_w = (const float*)d_in[8];
  const float* ln2_w = (const float*)d_in[9];
  const float* wqkv = (const float*)d_in[10];
  const float* wo = (const float*)d_in[11];
  const float* w1 = (const float*)d_in[12];
  const float* w2 = (const float*)d_in[13];
  float* out = (float*)d_out;

  // ws: x(4MB) y(4MB) h(4MB) R(6.3MB). Big dead-before-head scratch in d_out.
  float* x = (float*)d_ws;
  float* y = x + (size_t)kT * kD;
  float* h = y + (size_t)kT * kD;
  float* R = h + (size_t)kT * kD;
  float* qkv = out;                        // 12MB of d_out (131MB)
  float* ff = out + (size_t)kT * 3 * kD;   // next 16MB of d_out

  cayley_kernel<<<kL * kG, 64, 0, stream>>>(skew_upper, R);
  embed_kernel<<<kT * kD / 4 / 256, 256, 0, stream>>>(tokens, embed_w, x);

  for (int l = 0; l < kL; ++l) {
    rms_kernel<true><<<kT, 256, 0, stream>>>(x, ln1_w, layer_gamma + (size_t)l * kD,
                                             layer_beta + (size_t)l * kD, h);
    gemm_kernel<0, false><<<dim3(3 * kD / 64, kT / 64), 256, 0, stream>>>(
        h, wqkv, nullptr, qkv, kT, 3 * kD, kD);
    attn_kernel<<<dim3(kT, kH), 256, 0, stream>>>(qkv, h);
    gemm_kernel<1, false><<<dim3(kD / 64, kT / 64), 256, 0, stream>>>(
        h, wo, x, y, kT, kD, kD);
    rms_kernel<false><<<kT, 256, 0, stream>>>(y, ln2_w, nullptr, nullptr, h);
    gemm_kernel<2, false><<<dim3(kFF / 64, kT / 64), 256, 0, stream>>>(
        h, w1, nullptr, ff, kT, kFF, kD);
    gemm_kernel<1, false><<<dim3(kD / 64, kT / 64), 256, 0, stream>>>(
        ff, w2, y, y, kT, kD, kFF);
    blend_rot_kernel<<<kT, 256, 0, stream>>>(x, y, iter_scale, l, R, x);
  }

  rms_kernel<false><<<kT, 256, 0, stream>>>(x, norm_w, nullptr, nullptr, h);
  gemm_kernel<0, true><<<dim3(kV / 64, kT / 64), 256, 0, stream>>>(
      h, lm_head_w, nullptr, out, kT, kV, kD);
}

// Round 2
// 15688.058 us; speedup vs baseline: 1.5813x; 1.5813x over previous
//
#include <hip/hip_runtime.h>
#include <hip/hip_bf16.h>
#include <math.h>

// Model dims
constexpr int kD = 1024;
constexpr int kH = 16;
constexpr int kV = 32000;
constexpr int kT = 1024;
constexpr int kG = 16;
constexpr int kFF = 4096;
constexpr int kL = 24;
constexpr int kNTRI = 2016;
#define EPSF 1e-6f

typedef __bf16 bf16x8 __attribute__((ext_vector_type(8)));
typedef __bf16 bf16x4 __attribute__((ext_vector_type(4)));
typedef float f32x4 __attribute__((ext_vector_type(4)));

// ---------------------------------------------------------------------------
// Cayley transform: R = (I - A/2)^-1 (I + A/2), one block per (layer,group).
// ---------------------------------------------------------------------------
__global__ __launch_bounds__(64) void cayley_kernel(const float* __restrict__ skew,
                                                    float* __restrict__ R) {
  int lg = blockIdx.x;
  int r = threadIdx.x;
  __shared__ float Ms[64][65];
  __shared__ float Bs[64][65];
  const float* su = skew + (size_t)lg * kNTRI;
  for (int c = 0; c < 64; ++c) {
    float a = 0.f;
    if (r < c) a = su[r * (127 - r) / 2 + (c - r - 1)];
    else if (r > c) a = -su[c * (127 - c) / 2 + (r - c - 1)];
    Ms[r][c] = (r == c ? 1.f : 0.f) - 0.5f * a;
    Bs[r][c] = (r == c ? 1.f : 0.f) + 0.5f * a;
  }
  __syncthreads();
  for (int k = 0; k < 64; ++k) {
    if (r == k) {
      float piv = 1.f / Ms[k][k];
      for (int c = 0; c < 64; ++c) { Ms[k][c] *= piv; Bs[k][c] *= piv; }
    }
    __syncthreads();
    if (r != k) {
      float f = Ms[r][k];
      for (int c = 0; c < 64; ++c) { Ms[r][c] -= f * Ms[k][c]; Bs[r][c] -= f * Bs[k][c]; }
    }
    __syncthreads();
  }
  float* Ro = R + ((size_t)lg * 64 + r) * 64;
  for (int c = 0; c < 64; ++c) Ro[c] = Bs[r][c];
}

// ---------------------------------------------------------------------------
// Embedding gather, float4-vectorized.
// ---------------------------------------------------------------------------
__global__ __launch_bounds__(256) void embed_kernel(const int* __restrict__ tok,
                                                    const float* __restrict__ ew,
                                                    float* __restrict__ x) {
  int i = blockIdx.x * 256 + threadIdx.x;
  int t = i >> 8;
  int d4 = i & 255;
  int v = tok[t];
  reinterpret_cast<float4*>(x)[i] =
      reinterpret_cast<const float4*>(ew + (size_t)v * kD)[d4];
}

// ---------------------------------------------------------------------------
// Weight convert+transpose: W f32 [K][N] -> WT bf16 [N][K]. 64x64 tiles.
// ---------------------------------------------------------------------------
__global__ __launch_bounds__(256) void convt_kernel(const float* __restrict__ W,
                                                    __bf16* __restrict__ WT,
                                                    int K, int N) {
  __shared__ float tile[64][65];
  int t = threadIdx.x;
  int n0 = blockIdx.x * 64, k0 = blockIdx.y * 64;
#pragma unroll
  for (int r = 0; r < 4; ++r) {
    int kr = r * 16 + (t >> 4);
    int nc = (t & 15) * 4;
    float4 v = *reinterpret_cast<const float4*>(&W[(size_t)(k0 + kr) * N + n0 + nc]);
    tile[kr][nc + 0] = v.x;
    tile[kr][nc + 1] = v.y;
    tile[kr][nc + 2] = v.z;
    tile[kr][nc + 3] = v.w;
  }
  __syncthreads();
#pragma unroll
  for (int r = 0; r < 2; ++r) {
    int idx = r * 256 + t;
    int nrow = idx >> 3, kc = (idx & 7) * 8;
    bf16x8 v;
#pragma unroll
    for (int j = 0; j < 8; ++j) v[j] = (__bf16)tile[kc + j][nrow];
    *reinterpret_cast<bf16x8*>(&WT[(size_t)(n0 + nrow) * K + k0 + kc]) = v;
  }
}

// ---------------------------------------------------------------------------
// RMSNorm -> bf16 out. AFFINE: out = rms(x)*w*gamma + beta
// ---------------------------------------------------------------------------
template <bool AFFINE>
__global__ __launch_bounds__(256) void rms_kernel(const float* __restrict__ x,
                                                  const float* __restrict__ w,
                                                  const float* __restrict__ gamma,
                                                  const float* __restrict__ beta,
                                                  __bf16* __restrict__ out) {
  int t = blockIdx.x, tid = threadIdx.x;
  __shared__ float red[256];
  float4 xv = reinterpret_cast<const float4*>(x + (size_t)t * kD)[tid];
  red[tid] = xv.x * xv.x + xv.y * xv.y + xv.z * xv.z + xv.w * xv.w;
  __syncthreads();
  for (int off = 128; off > 0; off >>= 1) {
    if (tid < off) red[tid] += red[tid + off];
    __syncthreads();
  }
  float rms = rsqrtf(red[0] / (float)kD + EPSF);
  float4 wv = reinterpret_cast<const float4*>(w)[tid];
  float o0 = xv.x * rms * wv.x;
  float o1 = xv.y * rms * wv.y;
  float o2 = xv.z * rms * wv.z;
  float o3 = xv.w * rms * wv.w;
  if (AFFINE) {
    float4 gv = reinterpret_cast<const float4*>(gamma)[tid];
    float4 bv = reinterpret_cast<const float4*>(beta)[tid];
    o0 = o0 * gv.x + bv.x;
    o1 = o1 * gv.y + bv.y;
    o2 = o2 * gv.z + bv.z;
    o3 = o3 * gv.w + bv.w;
  }
  bf16x4 ov;
  ov[0] = (__bf16)o0; ov[1] = (__bf16)o1; ov[2] = (__bf16)o2; ov[3] = (__bf16)o3;
  *reinterpret_cast<bf16x4*>(out + (size_t)t * kD + tid * 4) = ov;
}

// ---------------------------------------------------------------------------
// bf16 MFMA GEMM: C[M,N] = A[M,K](bf16) @ B[N,K]^T (+ epilogue)
// BF32: B is f32 [N][K], converted during staging (lm_head path).
// EPI: 0 = f32 store, 1 = f32 store acc+res, 2 = gelu(tanh) -> bf16 store.
// 128x128 tile, BK=64, 256 threads = 4 waves (2x2), each wave 64x64 via
// 4x4 frags of v_mfma_f32_16x16x32_bf16. LDS row stride 72 (conflict-free).
// ---------------------------------------------------------------------------
template <int EPI, bool BF32>
__global__ __launch_bounds__(256) void gemm_mfma_kernel(
    const __bf16* __restrict__ A, const void* __restrict__ Bv,
    const float* __restrict__ res, void* __restrict__ Cv,
    int M, int N, int K) {
  constexpr int LDT = 72;
  __shared__ __bf16 As[128 * LDT];
  __shared__ __bf16 Bs[128 * LDT];
  int tid = threadIdx.x;
  int bm = blockIdx.y * 128, bn = blockIdx.x * 128;
  int w = tid >> 6, lane = tid & 63;
  int wr = (w >> 1) * 64, wc = (w & 1) * 64;
  int lrow = lane & 15, lkb = (lane >> 4) * 8;
  f32x4 acc[4][4] = {};

  const __bf16* B16 = (const __bf16*)Bv;
  const float* B32 = (const float*)Bv;

  for (int k0 = 0; k0 < K; k0 += 64) {
#pragma unroll
    for (int rrep = 0; rrep < 4; ++rrep) {
      int cid = rrep * 256 + tid;
      int row = cid >> 3, kc = (cid & 7) << 3;
      *reinterpret_cast<bf16x8*>(&As[row * LDT + kc]) =
          *reinterpret_cast<const bf16x8*>(&A[(size_t)(bm + row) * K + k0 + kc]);
    }
#pragma unroll
    for (int rrep = 0; rrep < 4; ++rrep) {
      int cid = rrep * 256 + tid;
      int row = cid >> 3, kc = (cid & 7) << 3;
      if (!BF32) {
        *reinterpret_cast<bf16x8*>(&Bs[row * LDT + kc]) =
            *reinterpret_cast<const bf16x8*>(&B16[(size_t)(bn + row) * K + k0 + kc]);
      } else {
        const float* src = &B32[(size_t)(bn + row) * K + k0 + kc];
        float4 f0 = *reinterpret_cast<const float4*>(src);
        float4 f1 = *reinterpret_cast<const float4*>(src + 4);
        bf16x8 v;
        v[0] = (__bf16)f0.x; v[1] = (__bf16)f0.y;
        v[2] = (__bf16)f0.z; v[3] = (__bf16)f0.w;
        v[4] = (__bf16)f1.x; v[5] = (__bf16)f1.y;
        v[6] = (__bf16)f1.z; v[7] = (__bf16)f1.w;
        *reinterpret_cast<bf16x8*>(&Bs[row * LDT + kc]) = v;
      }
    }
    __syncthreads();
#pragma unroll
    for (int ks = 0; ks < 2; ++ks) {
      bf16x8 af[4], bg[4];
#pragma unroll
      for (int i = 0; i < 4; ++i)
        af[i] = *reinterpret_cast<const bf16x8*>(
            &As[(wr + i * 16 + lrow) * LDT + ks * 32 + lkb]);
#pragma unroll
      for (int j = 0; j < 4; ++j)
        bg[j] = *reinterpret_cast<const bf16x8*>(
            &Bs[(wc + j * 16 + lrow) * LDT + ks * 32 + lkb]);
#pragma unroll
      for (int i = 0; i < 4; ++i)
#pragma unroll
        for (int j = 0; j < 4; ++j)
          acc[i][j] = __builtin_amdgcn_mfma_f32_16x16x32_bf16(af[i], bg[j],
                                                              acc[i][j], 0, 0, 0);
    }
    __syncthreads();
  }

  int crow0 = bm + wr + (lane >> 4) * 4;
  int ccol0 = bn + wc + lrow;
#pragma unroll
  for (int i = 0; i < 4; ++i) {
#pragma unroll
    for (int j = 0; j < 4; ++j) {
#pragma unroll
      for (int r = 0; r < 4; ++r) {
        int row = crow0 + i * 16 + r;
        int col = ccol0 + j * 16;
        size_t idx = (size_t)row * N + col;
        float v = acc[i][j][r];
        if (EPI == 1) v += res[idx];
        if (EPI == 2) {
          float u = v;
          v = 0.5f * u * (1.f + tanhf(0.7978845608028654f * (u + 0.044715f * u * u * u)));
          ((__bf16*)Cv)[idx] = (__bf16)v;
        } else {
          ((float*)Cv)[idx] = v;
        }
      }
    }
  }
}

// ---------------------------------------------------------------------------
// Causal attention, one block per (q, head). qkv f32 [T][3D]; bf16 out.
// ---------------------------------------------------------------------------
__global__ __launch_bounds__(256) void attn_kernel(const float* __restrict__ qkv,
                                                   __bf16* __restrict__ out) {
  int q = blockIdx.x, h = blockIdx.y;
  int tid = threadIdx.x;
  __shared__ float qv[64];
  __shared__ float sc[kT];
  __shared__ float red[256];
  __shared__ float part[4][64];
  const float* qrow = qkv + (size_t)q * (3 * kD) + h * 64;
  if (tid < 64) qv[tid] = qrow[tid];
  __syncthreads();
  int nk = q + 1;
  float lmax = -1e30f;
  for (int k = tid; k < nk; k += 256) {
    const float* krow = qkv + (size_t)k * (3 * kD) + kD + h * 64;
    float s = 0.f;
#pragma unroll
    for (int d = 0; d < 64; d += 4) {
      float4 k4 = *reinterpret_cast<const float4*>(krow + d);
      float4 q4 = *reinterpret_cast<const float4*>(&qv[d]);
      s += q4.x * k4.x + q4.y * k4.y + q4.z * k4.z + q4.w * k4.w;
    }
    s *= 0.125f;
    sc[k] = s;
    lmax = fmaxf(lmax, s);
  }
  red[tid] = lmax;
  __syncthreads();
  for (int off = 128; off > 0; off >>= 1) {
    if (tid < off) red[tid] = fmaxf(red[tid], red[tid + off]);
    __syncthreads();
  }
  float m = red[0];
  __syncthreads();
  float lsum = 0.f;
  for (int k = tid; k < nk; k += 256) {
    float e = expf(sc[k] - m);
    sc[k] = e;
    lsum += e;
  }
  red[tid] = lsum;
  __syncthreads();
  for (int off = 128; off > 0; off >>= 1) {
    if (tid < off) red[tid] += red[tid + off];
    __syncthreads();
  }
  float inv = 1.f / red[0];
  int w = tid >> 6, lane = tid & 63;
  float accv = 0.f;
  for (int k = w; k < nk; k += 4)
    accv += sc[k] * qkv[(size_t)k * (3 * kD) + 2 * kD + h * 64 + lane];
  part[w][lane] = accv;
  __syncthreads();
  if (tid < 64) {
    float o = (part[0][tid] + part[1][tid] + part[2][tid] + part[3][tid]) * inv;
    out[(size_t)q * kD + h * 64 + tid] = (__bf16)o;
  }
}

// ---------------------------------------------------------------------------
// Fused residual blend + group rotation (f32).
// ---------------------------------------------------------------------------
__global__ __launch_bounds__(256) void blend_rot_kernel(const float* __restrict__ x,
                                                        const float* __restrict__ y,
                                                        const float* __restrict__ iscale,
                                                        int l,
                                                        const float* __restrict__ R,
                                                        float* __restrict__ xout) {
  int t = blockIdx.x, tid = threadIdx.x;
  __shared__ float xb[kD];
  float s = iscale[l];
  float4 xv = reinterpret_cast<const float4*>(x + (size_t)t * kD)[tid];
  float4 yv = reinterpret_cast<const float4*>(y + (size_t)t * kD)[tid];
  xb[4 * tid + 0] = xv.x + (yv.x - xv.x) * s;
  xb[4 * tid + 1] = xv.y + (yv.y - xv.y) * s;
  xb[4 * tid + 2] = xv.z + (yv.z - xv.z) * s;
  xb[4 * tid + 3] = xv.w + (yv.w - xv.w) * s;
  __syncthreads();
  const float* Rl = R + (size_t)l * kG * 64 * 64;
#pragma unroll
  for (int rep = 0; rep < 4; ++rep) {
    int oi = rep * 256 + tid;
    int gr = oi >> 6, j = oi & 63;
    const float* Rg = Rl + ((size_t)gr << 12);
    const float* xg = &xb[gr << 6];
    float acc = 0.f;
#pragma unroll 8
    for (int i = 0; i < 64; ++i) acc += xg[i] * Rg[(i << 6) + j];
    xout[(size_t)t * kD + oi] = acc;
  }
}

// ---------------------------------------------------------------------------
extern "C" void kernel_launch(void* const* d_in, const int* in_sizes, int n_in,
                              void* d_out, int out_size, void* d_ws, size_t ws_size,
                              hipStream_t stream) {
  const int* tokens = (const int*)d_in[0];
  const float* embed_w = (const float*)d_in[1];
  const float* lm_head_w = (const float*)d_in[2];
  const float* norm_w = (const float*)d_in[3];
  const float* layer_gamma = (const float*)d_in[4];
  const float* layer_beta = (const float*)d_in[5];
  const float* iter_scale = (const float*)d_in[6];
  const float* skew_upper = (const float*)d_in[7];
  const float* ln1_w = (const float*)d_in[8];
  const float* ln2_w = (const float*)d_in[9];
  const float* wqkv = (const float*)d_in[10];
  const float* wo = (const float*)d_in[11];
  const float* w1 = (const float*)d_in[12];
  const float* w2 = (const float*)d_in[13];
  float* out = (float*)d_out;

  // ws: x(4MB) y(4MB) hb(2MB) ab(2MB) R(6.3MB)  [~18.3MB, same as round 1]
  float* x = (float*)d_ws;
  float* y = x + (size_t)kT * kD;
  __bf16* hb = (__bf16*)(y + (size_t)kT * kD);
  __bf16* ab = hb + (size_t)kT * kD;
  float* R = (float*)(ab + (size_t)kT * kD);

  // d_out scratch (all dead before final lm_head GEMM writes out):
  float* qkv = out;                                  // 3.1M f32
  __bf16* ffb = (__bf16*)(out + 3145728);            // 4.2M bf16
  __bf16* wqkvT = (__bf16*)(out + 5242880);          // [3072][1024]
  __bf16* woT = (__bf16*)(out + 6815744);            // [1024][1024]
  __bf16* w1T = (__bf16*)(out + 7340032);            // [4096][1024]
  __bf16* w2T = (__bf16*)(out + 9437184);            // [1024][4096]

  cayley_kernel<<<kL * kG, 64, 0, stream>>>(skew_upper, R);
  embed_kernel<<<kT * kD / 4 / 256, 256, 0, stream>>>(tokens, embed_w, x);
  convt_kernel<<<dim3(3 * kD / 64, kD / 64), 256, 0, stream>>>(wqkv, wqkvT, kD, 3 * kD);
  convt_kernel<<<dim3(kD / 64, kD / 64), 256, 0, stream>>>(wo, woT, kD, kD);
  convt_kernel<<<dim3(kFF / 64, kD / 64), 256, 0, stream>>>(w1, w1T, kD, kFF);
  convt_kernel<<<dim3(kD / 64, kFF / 64), 256, 0, stream>>>(w2, w2T, kFF, kD);

  for (int l = 0; l < kL; ++l) {
    rms_kernel<true><<<kT, 256, 0, stream>>>(x, ln1_w, layer_gamma + (size_t)l * kD,
                                             layer_beta + (size_t)l * kD, hb);
    gemm_mfma_kernel<0, false><<<dim3(3 * kD / 128, kT / 128), 256, 0, stream>>>(
        hb, wqkvT, nullptr, qkv, kT, 3 * kD, kD);
    attn_kernel<<<dim3(kT, kH), 256, 0, stream>>>(qkv, ab);
    gemm_mfma_kernel<1, false><<<dim3(kD / 128, kT / 128), 256, 0, stream>>>(
        ab, woT, x, y, kT, kD, kD);
    rms_kernel<false><<<kT, 256, 0, stream>>>(y, ln2_w, nullptr, nullptr, hb);
    gemm_mfma_kernel<2, false><<<dim3(kFF / 128, kT / 128), 256, 0, stream>>>(
        hb, w1T, nullptr, ffb, kT, kFF, kD);
    gemm_mfma_kernel<1, false><<<dim3(kD / 128, kT / 128), 256, 0, stream>>>(
        ffb, w2T, y, y, kT, kD, kFF);
    blend_rot_kernel<<<kT, 256, 0, stream>>>(x, y, iter_scale, l, R, x);
  }

  rms_kernel<false><<<kT, 256, 0, stream>>>(x, norm_w, nullptr, nullptr, hb);
  gemm_mfma_kernel<0, true><<<dim3(kV / 128, kT / 128), 256, 0, stream>>>(
      hb, lm_head_w, nullptr, out, kT, kV, kD);
}

// Round 4
// 5626.270 us; speedup vs baseline: 4.4092x; 2.7884x over previous
//
#include <hip/hip_runtime.h>
#include <hip/hip_bf16.h>
#include <math.h>

// Model dims
constexpr int kD = 1024;
constexpr int kH = 16;
constexpr int kV = 32000;
constexpr int kT = 1024;
constexpr int kG = 16;
constexpr int kFF = 4096;
constexpr int kL = 24;
constexpr int kNTRI = 2016;
#define EPSF 1e-6f
#define L2E 1.44269504088896f

typedef __bf16 bf16x8 __attribute__((ext_vector_type(8)));
typedef __bf16 bf16x4 __attribute__((ext_vector_type(4)));
typedef float f32x4 __attribute__((ext_vector_type(4)));

// ---------------------------------------------------------------------------
// Cayley transform: R = (I - A/2)^-1 (I + A/2), one block per (layer,group).
// ---------------------------------------------------------------------------
__global__ __launch_bounds__(64) void cayley_kernel(const float* __restrict__ skew,
                                                    float* __restrict__ R) {
  int lg = blockIdx.x;
  int r = threadIdx.x;
  __shared__ float Ms[64][65];
  __shared__ float Bs[64][65];
  const float* su = skew + (size_t)lg * kNTRI;
  for (int c = 0; c < 64; ++c) {
    float a = 0.f;
    if (r < c) a = su[r * (127 - r) / 2 + (c - r - 1)];
    else if (r > c) a = -su[c * (127 - c) / 2 + (r - c - 1)];
    Ms[r][c] = (r == c ? 1.f : 0.f) - 0.5f * a;
    Bs[r][c] = (r == c ? 1.f : 0.f) + 0.5f * a;
  }
  __syncthreads();
  for (int k = 0; k < 64; ++k) {
    if (r == k) {
      float piv = 1.f / Ms[k][k];
      for (int c = 0; c < 64; ++c) { Ms[k][c] *= piv; Bs[k][c] *= piv; }
    }
    __syncthreads();
    if (r != k) {
      float f = Ms[r][k];
      for (int c = 0; c < 64; ++c) { Ms[r][c] -= f * Ms[k][c]; Bs[r][c] -= f * Bs[k][c]; }
    }
    __syncthreads();
  }
  float* Ro = R + ((size_t)lg * 64 + r) * 64;
  for (int c = 0; c < 64; ++c) Ro[c] = Bs[r][c];
}

// ---------------------------------------------------------------------------
// Embedding gather, float4-vectorized.
// ---------------------------------------------------------------------------
__global__ __launch_bounds__(256) void embed_kernel(const int* __restrict__ tok,
                                                    const float* __restrict__ ew,
                                                    float* __restrict__ x) {
  int i = blockIdx.x * 256 + threadIdx.x;
  int t = i >> 8;
  int d4 = i & 255;
  int v = tok[t];
  reinterpret_cast<float4*>(x)[i] =
      reinterpret_cast<const float4*>(ew + (size_t)v * kD)[d4];
}

// ---------------------------------------------------------------------------
// Weight convert+transpose: W f32 [K][N] -> WT bf16 [N][K]. 64x64 tiles.
// ---------------------------------------------------------------------------
__global__ __launch_bounds__(256) void convt_kernel(const float* __restrict__ W,
                                                    __bf16* __restrict__ WT,
                                                    int K, int N) {
  __shared__ float tile[64][65];
  int t = threadIdx.x;
  int n0 = blockIdx.x * 64, k0 = blockIdx.y * 64;
#pragma unroll
  for (int r = 0; r < 4; ++r) {
    int kr = r * 16 + (t >> 4);
    int nc = (t & 15) * 4;
    float4 v = *reinterpret_cast<const float4*>(&W[(size_t)(k0 + kr) * N + n0 + nc]);
    tile[kr][nc + 0] = v.x;
    tile[kr][nc + 1] = v.y;
    tile[kr][nc + 2] = v.z;
    tile[kr][nc + 3] = v.w;
  }
  __syncthreads();
#pragma unroll
  for (int r = 0; r < 2; ++r) {
    int idx = r * 256 + t;
    int nrow = idx >> 3, kc = (idx & 7) * 8;
    bf16x8 v;
#pragma unroll
    for (int j = 0; j < 8; ++j) v[j] = (__bf16)tile[kc + j][nrow];
    *reinterpret_cast<bf16x8*>(&WT[(size_t)(n0 + nrow) * K + k0 + kc]) = v;
  }
}

// ---------------------------------------------------------------------------
// RMSNorm -> bf16 out. AFFINE: out = rms(x)*w*gamma + beta
// ---------------------------------------------------------------------------
template <bool AFFINE>
__global__ __launch_bounds__(256) void rms_kernel(const float* __restrict__ x,
                                                  const float* __restrict__ w,
                                                  const float* __restrict__ gamma,
                                                  const float* __restrict__ beta,
                                                  __bf16* __restrict__ out) {
  int t = blockIdx.x, tid = threadIdx.x;
  __shared__ float red[256];
  float4 xv = reinterpret_cast<const float4*>(x + (size_t)t * kD)[tid];
  red[tid] = xv.x * xv.x + xv.y * xv.y + xv.z * xv.z + xv.w * xv.w;
  __syncthreads();
  for (int off = 128; off > 0; off >>= 1) {
    if (tid < off) red[tid] += red[tid + off];
    __syncthreads();
  }
  float rms = rsqrtf(red[0] / (float)kD + EPSF);
  float4 wv = reinterpret_cast<const float4*>(w)[tid];
  float o0 = xv.x * rms * wv.x;
  float o1 = xv.y * rms * wv.y;
  float o2 = xv.z * rms * wv.z;
  float o3 = xv.w * rms * wv.w;
  if (AFFINE) {
    float4 gv = reinterpret_cast<const float4*>(gamma)[tid];
    float4 bv = reinterpret_cast<const float4*>(beta)[tid];
    o0 = o0 * gv.x + bv.x;
    o1 = o1 * gv.y + bv.y;
    o2 = o2 * gv.z + bv.z;
    o3 = o3 * gv.w + bv.w;
  }
  bf16x4 ov;
  ov[0] = (__bf16)o0; ov[1] = (__bf16)o1; ov[2] = (__bf16)o2; ov[3] = (__bf16)o3;
  *reinterpret_cast<bf16x4*>(out + (size_t)t * kD + tid * 4) = ov;
}

// ---------------------------------------------------------------------------
// bf16 MFMA GEMM: C[M,N] = A[M,K](bf16) @ B[N,K]^T (+ epilogue)
// BF32: B is f32 [N][K], converted during staging (lm_head path).
// EPI: 0 = f32 store, 1 = f32 store acc+res, 2 = gelu(tanh)->bf16,
//      3 = bf16 store.
// 128x128 tile, BK=64, 256 threads = 4 waves (2x2), each wave 64x64 via
// 4x4 frags of v_mfma_f32_16x16x32_bf16. LDS row stride 72 (conflict-free).
// ---------------------------------------------------------------------------
template <int EPI, bool BF32>
__global__ __launch_bounds__(256) void gemm_mfma_kernel(
    const __bf16* __restrict__ A, const void* __restrict__ Bv,
    const float* res, void* __restrict__ Cv,
    int M, int N, int K) {
  constexpr int LDT = 72;
  __shared__ __bf16 As[128 * LDT];
  __shared__ __bf16 Bs[128 * LDT];
  int tid = threadIdx.x;
  int bm = blockIdx.y * 128, bn = blockIdx.x * 128;
  int w = tid >> 6, lane = tid & 63;
  int wr = (w >> 1) * 64, wc = (w & 1) * 64;
  int lrow = lane & 15, lkb = (lane >> 4) * 8;
  f32x4 acc[4][4] = {};

  const __bf16* B16 = (const __bf16*)Bv;
  const float* B32 = (const float*)Bv;

  for (int k0 = 0; k0 < K; k0 += 64) {
#pragma unroll
    for (int rrep = 0; rrep < 4; ++rrep) {
      int cid = rrep * 256 + tid;
      int row = cid >> 3, kc = (cid & 7) << 3;
      *reinterpret_cast<bf16x8*>(&As[row * LDT + kc]) =
          *reinterpret_cast<const bf16x8*>(&A[(size_t)(bm + row) * K + k0 + kc]);
    }
#pragma unroll
    for (int rrep = 0; rrep < 4; ++rrep) {
      int cid = rrep * 256 + tid;
      int row = cid >> 3, kc = (cid & 7) << 3;
      if (!BF32) {
        *reinterpret_cast<bf16x8*>(&Bs[row * LDT + kc]) =
            *reinterpret_cast<const bf16x8*>(&B16[(size_t)(bn + row) * K + k0 + kc]);
      } else {
        const float* src = &B32[(size_t)(bn + row) * K + k0 + kc];
        float4 f0 = *reinterpret_cast<const float4*>(src);
        float4 f1 = *reinterpret_cast<const float4*>(src + 4);
        bf16x8 v;
        v[0] = (__bf16)f0.x; v[1] = (__bf16)f0.y;
        v[2] = (__bf16)f0.z; v[3] = (__bf16)f0.w;
        v[4] = (__bf16)f1.x; v[5] = (__bf16)f1.y;
        v[6] = (__bf16)f1.z; v[7] = (__bf16)f1.w;
        *reinterpret_cast<bf16x8*>(&Bs[row * LDT + kc]) = v;
      }
    }
    __syncthreads();
#pragma unroll
    for (int ks = 0; ks < 2; ++ks) {
      bf16x8 af[4], bg[4];
#pragma unroll
      for (int i = 0; i < 4; ++i)
        af[i] = *reinterpret_cast<const bf16x8*>(
            &As[(wr + i * 16 + lrow) * LDT + ks * 32 + lkb]);
#pragma unroll
      for (int j = 0; j < 4; ++j)
        bg[j] = *reinterpret_cast<const bf16x8*>(
            &Bs[(wc + j * 16 + lrow) * LDT + ks * 32 + lkb]);
#pragma unroll
      for (int i = 0; i < 4; ++i)
#pragma unroll
        for (int j = 0; j < 4; ++j)
          acc[i][j] = __builtin_amdgcn_mfma_f32_16x16x32_bf16(af[i], bg[j],
                                                              acc[i][j], 0, 0, 0);
    }
    __syncthreads();
  }

  int crow0 = bm + wr + (lane >> 4) * 4;
  int ccol0 = bn + wc + lrow;
#pragma unroll
  for (int i = 0; i < 4; ++i) {
#pragma unroll
    for (int j = 0; j < 4; ++j) {
#pragma unroll
      for (int r = 0; r < 4; ++r) {
        int row = crow0 + i * 16 + r;
        int col = ccol0 + j * 16;
        size_t idx = (size_t)row * N + col;
        float v = acc[i][j][r];
        if (EPI == 1) v += res[idx];
        if (EPI == 2) {
          float u = v;
          v = 0.5f * u * (1.f + tanhf(0.7978845608028654f * (u + 0.044715f * u * u * u)));
        }
        if (EPI == 2 || EPI == 3) ((__bf16*)Cv)[idx] = (__bf16)v;
        else ((float*)Cv)[idx] = v;
      }
    }
  }
}

// ---------------------------------------------------------------------------
// Flash attention (causal), bf16 MFMA. qkv bf16 [T][3D]; out bf16 [T][D].
// Block = (q-tile of 64 rows, head); 4 waves, wave w owns q-rows [16w,16w+16).
// Per KV tile of 64: K staged row-major swizzled, V staged transposed
// swizzled; QK^T and PV via mfma_f32_16x16x32_bf16; online softmax with
// 16-lane shfl_xor row reductions; P via per-wave swizzled LDS tile.
// ---------------------------------------------------------------------------
__global__ __launch_bounds__(256) void fattn_kernel(const __bf16* __restrict__ qkv,
                                                    __bf16* __restrict__ out) {
  __shared__ __bf16 Ks[64 * 64];
  __shared__ __bf16 Vt[64 * 64];
  __shared__ __bf16 Ps[4 * 16 * 64];
  int tid = threadIdx.x;
  int bq = blockIdx.x * 64;
  int h = blockIdx.y;
  int w = tid >> 6, lane = tid & 63;
  int g = lane >> 4, lr = lane & 15;

  // Q fragments, scaled by 1/sqrt(64) (exact in bf16).
  bf16x8 qf[2];
  const __bf16* qbase = qkv + (size_t)(bq + w * 16 + lr) * (3 * kD) + h * 64;
#pragma unroll
  for (int ks = 0; ks < 2; ++ks) {
    bf16x8 v = *reinterpret_cast<const bf16x8*>(qbase + ks * 32 + g * 8);
#pragma unroll
    for (int j = 0; j < 8; ++j) qf[ks][j] = (__bf16)((float)v[j] * 0.125f);
  }

  f32x4 acc[4] = {};
  float m[4], lsum[4];
#pragma unroll
  for (int r = 0; r < 4; ++r) { m[r] = -1e30f; lsum[r] = 0.f; }

  // staging indices
  int srow = tid >> 2, sseg = tid & 3;              // K: 64 rows x 4 segs of 32B
  int vk = tid & 63, vd0 = (tid >> 6) * 16;         // V: 64 keys x 4 d-blocks of 16
  char* KsB = (char*)Ks;
  char* VtB = (char*)Vt;
  char* PwB = (char*)(Ps + w * (16 * 64));

  int ntiles = bq / 64 + 1;
  for (int kt = 0; kt < ntiles; ++kt) {
    // ---- stage K tile (row-major, XOR-swizzled 16B granules) ----
    {
      const __bf16* src = qkv + (size_t)(kt * 64 + srow) * (3 * kD) + kD + h * 64 + sseg * 16;
      bf16x8 a = *reinterpret_cast<const bf16x8*>(src);
      bf16x8 b = *reinterpret_cast<const bf16x8*>(src + 8);
      int bc = sseg * 32, sw = (srow & 7) << 4;
      *reinterpret_cast<bf16x8*>(KsB + srow * 128 + (bc ^ sw)) = a;
      *reinterpret_cast<bf16x8*>(KsB + srow * 128 + ((bc + 16) ^ sw)) = b;
      // ---- stage V transposed ----
      const __bf16* vsrc = qkv + (size_t)(kt * 64 + vk) * (3 * kD) + 2 * kD + h * 64 + vd0;
      bf16x8 v0 = *reinterpret_cast<const bf16x8*>(vsrc);
      bf16x8 v1 = *reinterpret_cast<const bf16x8*>(vsrc + 8);
#pragma unroll
      for (int i = 0; i < 8; ++i) {
        int d = vd0 + i;
        *((__bf16*)(VtB + d * 128 + ((vk * 2) ^ ((d & 7) << 4)))) = v0[i];
        d = vd0 + 8 + i;
        *((__bf16*)(VtB + d * 128 + ((vk * 2) ^ ((d & 7) << 4)))) = v1[i];
      }
    }
    __syncthreads();

    bool diag = (kt == ntiles - 1);
    int jmax = diag ? w : 3;

    // ---- QK^T ----
    f32x4 s[4];
#pragma unroll
    for (int j = 0; j < 4; ++j) {
      if (j <= jmax) {
        int krow = j * 16 + lr, sw = (krow & 7) << 4;
        bf16x8 kb0 = *reinterpret_cast<const bf16x8*>(KsB + krow * 128 + ((g * 16) ^ sw));
        bf16x8 kb1 = *reinterpret_cast<const bf16x8*>(KsB + krow * 128 + ((64 + g * 16) ^ sw));
        f32x4 z = {};
        z = __builtin_amdgcn_mfma_f32_16x16x32_bf16(qf[0], kb0, z, 0, 0, 0);
        s[j] = __builtin_amdgcn_mfma_f32_16x16x32_bf16(qf[1], kb1, z, 0, 0, 0);
      } else {
        s[j] = f32x4{-1e30f, -1e30f, -1e30f, -1e30f};
      }
    }
    // diagonal mask: only subtile j==w is partial; mask key-lane lr > row g*4+r
    if (diag) {
#pragma unroll
      for (int r = 0; r < 4; ++r)
        if (lr > g * 4 + r) s[w][r] = -1e30f;
    }

    // ---- online softmax (rows = g*4+r, reduce over 16 lanes) ----
    float p[4][4];
#pragma unroll
    for (int r = 0; r < 4; ++r) {
      float mt = fmaxf(fmaxf(s[0][r], s[1][r]), fmaxf(s[2][r], s[3][r]));
#pragma unroll
      for (int o = 1; o < 16; o <<= 1) mt = fmaxf(mt, __shfl_xor(mt, o, 16));
      float mn = fmaxf(m[r], mt);
      float sc = exp2f((m[r] - mn) * L2E);
      float rs = 0.f;
#pragma unroll
      for (int j = 0; j < 4; ++j) {
        float e = exp2f((s[j][r] - mn) * L2E);
        p[j][r] = e;
        rs += e;
      }
#pragma unroll
      for (int o = 1; o < 16; o <<= 1) rs += __shfl_xor(rs, o, 16);
      lsum[r] = lsum[r] * sc + rs;
      m[r] = mn;
#pragma unroll
      for (int dt = 0; dt < 4; ++dt) acc[dt][r] *= sc;
    }

    // ---- write P tile (per-wave, swizzled) ----
#pragma unroll
    for (int j = 0; j < 4; ++j)
#pragma unroll
      for (int r = 0; r < 4; ++r) {
        int row = g * 4 + r;
        *((__bf16*)(PwB + row * 128 + (((j * 16 + lr) * 2) ^ ((row & 7) << 4)))) =
            (__bf16)p[j][r];
      }

    // ---- PV ----
    {
      int sw = (lr & 7) << 4;
      bf16x8 pa0 = *reinterpret_cast<const bf16x8*>(PwB + lr * 128 + ((g * 16) ^ sw));
      bf16x8 pa1 = *reinterpret_cast<const bf16x8*>(PwB + lr * 128 + ((64 + g * 16) ^ sw));
#pragma unroll
      for (int dt = 0; dt < 4; ++dt) {
        int vrow = dt * 16 + lr, vsw = (vrow & 7) << 4;
        bf16x8 vb0 = *reinterpret_cast<const bf16x8*>(VtB + vrow * 128 + ((g * 16) ^ vsw));
        bf16x8 vb1 = *reinterpret_cast<const bf16x8*>(VtB + vrow * 128 + ((64 + g * 16) ^ vsw));
        acc[dt] = __builtin_amdgcn_mfma_f32_16x16x32_bf16(pa0, vb0, acc[dt], 0, 0, 0);
        acc[dt] = __builtin_amdgcn_mfma_f32_16x16x32_bf16(pa1, vb1, acc[dt], 0, 0, 0);
      }
    }
    __syncthreads();
  }

  // ---- epilogue ----
#pragma unroll
  for (int r = 0; r < 4; ++r) {
    float inv = 1.f / lsum[r];
    int row = bq + w * 16 + g * 4 + r;
#pragma unroll
    for (int dt = 0; dt < 4; ++dt)
      out[(size_t)row * kD + h * 64 + dt * 16 + lr] = (__bf16)(acc[dt][r] * inv);
  }
}

// ---------------------------------------------------------------------------
// Fused residual blend + group rotation (f32).
// ---------------------------------------------------------------------------
__global__ __launch_bounds__(256) void blend_rot_kernel(const float* __restrict__ x,
                                                        const float* __restrict__ y,
                                                        const float* __restrict__ iscale,
                                                        int l,
                                                        const float* __restrict__ R,
                                                        float* __restrict__ xout) {
  int t = blockIdx.x, tid = threadIdx.x;
  __shared__ float xb[kD];
  float s = iscale[l];
  float4 xv = reinterpret_cast<const float4*>(x + (size_t)t * kD)[tid];
  float4 yv = reinterpret_cast<const float4*>(y + (size_t)t * kD)[tid];
  xb[4 * tid + 0] = xv.x + (yv.x - xv.x) * s;
  xb[4 * tid + 1] = xv.y + (yv.y - xv.y) * s;
  xb[4 * tid + 2] = xv.z + (yv.z - xv.z) * s;
  xb[4 * tid + 3] = xv.w + (yv.w - xv.w) * s;
  __syncthreads();
  const float* Rl = R + (size_t)l * kG * 64 * 64;
#pragma unroll
  for (int rep = 0; rep < 4; ++rep) {
    int oi = rep * 256 + tid;
    int gr = oi >> 6, j = oi & 63;
    const float* Rg = Rl + ((size_t)gr << 12);
    const float* xg = &xb[gr << 6];
    float acc = 0.f;
#pragma unroll 8
    for (int i = 0; i < 64; ++i) acc += xg[i] * Rg[(i << 6) + j];
    xout[(size_t)t * kD + oi] = acc;
  }
}

// ---------------------------------------------------------------------------
extern "C" void kernel_launch(void* const* d_in, const int* in_sizes, int n_in,
                              void* d_out, int out_size, void* d_ws, size_t ws_size,
                              hipStream_t stream) {
  const int* tokens = (const int*)d_in[0];
  const float* embed_w = (const float*)d_in[1];
  const float* lm_head_w = (const float*)d_in[2];
  const float* norm_w = (const float*)d_in[3];
  const float* layer_gamma = (const float*)d_in[4];
  const float* layer_beta = (const float*)d_in[5];
  const float* iter_scale = (const float*)d_in[6];
  const float* skew_upper = (const float*)d_in[7];
  const float* ln1_w = (const float*)d_in[8];
  const float* ln2_w = (const float*)d_in[9];
  const float* wqkv = (const float*)d_in[10];
  const float* wo = (const float*)d_in[11];
  const float* w1 = (const float*)d_in[12];
  const float* w2 = (const float*)d_in[13];
  float* out = (float*)d_out;

  // ws: x(4MB) y(4MB) hb(2MB) ab(2MB) R(6.3MB)
  float* x = (float*)d_ws;
  float* y = x + (size_t)kT * kD;
  __bf16* hb = (__bf16*)(y + (size_t)kT * kD);
  __bf16* ab = hb + (size_t)kT * kD;
  float* R = (float*)(ab + (size_t)kT * kD);

  // d_out scratch (all dead before final lm_head GEMM writes out):
  __bf16* qkvb = (__bf16*)out;                       // 3.1M bf16 (1572864 f32)
  __bf16* ffb = (__bf16*)(out + 1572864);            // 4.2M bf16 (2097152 f32)
  __bf16* wqkvT = (__bf16*)(out + 3670016);          // [3072][1024]
  __bf16* woT = (__bf16*)(out + 5242880);            // [1024][1024]
  __bf16* w1T = (__bf16*)(out + 5767168);            // [4096][1024]
  __bf16* w2T = (__bf16*)(out + 7864320);            // [1024][4096]

  cayley_kernel<<<kL * kG, 64, 0, stream>>>(skew_upper, R);
  embed_kernel<<<kT * kD / 4 / 256, 256, 0, stream>>>(tokens, embed_w, x);
  convt_kernel<<<dim3(3 * kD / 64, kD / 64), 256, 0, stream>>>(wqkv, wqkvT, kD, 3 * kD);
  convt_kernel<<<dim3(kD / 64, kD / 64), 256, 0, stream>>>(wo, woT, kD, kD);
  convt_kernel<<<dim3(kFF / 64, kD / 64), 256, 0, stream>>>(w1, w1T, kD, kFF);
  convt_kernel<<<dim3(kD / 64, kFF / 64), 256, 0, stream>>>(w2, w2T, kFF, kD);

  for (int l = 0; l < kL; ++l) {
    rms_kernel<true><<<kT, 256, 0, stream>>>(x, ln1_w, layer_gamma + (size_t)l * kD,
                                             layer_beta + (size_t)l * kD, hb);
    gemm_mfma_kernel<3, false><<<dim3(3 * kD / 128, kT / 128), 256, 0, stream>>>(
        hb, wqkvT, nullptr, qkvb, kT, 3 * kD, kD);
    fattn_kernel<<<dim3(kT / 64, kH), 256, 0, stream>>>(qkvb, ab);
    gemm_mfma_kernel<1, false><<<dim3(kD / 128, kT / 128), 256, 0, stream>>>(
        ab, woT, x, y, kT, kD, kD);
    rms_kernel<false><<<kT, 256, 0, stream>>>(y, ln2_w, nullptr, nullptr, hb);
    gemm_mfma_kernel<2, false><<<dim3(kFF / 128, kT / 128), 256, 0, stream>>>(
        hb, w1T, nullptr, ffb, kT, kFF, kD);
    gemm_mfma_kernel<1, false><<<dim3(kD / 128, kT / 128), 256, 0, stream>>>(
        ffb, w2T, y, y, kT, kD, kFF);
    blend_rot_kernel<<<kT, 256, 0, stream>>>(x, y, iter_scale, l, R, x);
  }

  rms_kernel<false><<<kT, 256, 0, stream>>>(x, norm_w, nullptr, nullptr, hb);
  gemm_mfma_kernel<0, true><<<dim3(kV / 128, kT / 128), 256, 0, stream>>>(
      hb, lm_head_w, nullptr, out, kT, kV, kD);
}